// Round 11
// baseline (347.582 us; speedup 1.0000x reference)
//
#include <hip/hip_runtime.h>
#include <hip/hip_bf16.h>
#include <math.h>

// Problem: B=2, H=12, S=2048, D=64. Device I/O: f32 inputs, f32 outputs.
#define B_SZ   2
#define NH     12
#define S_LEN  2048
#define D_HD   64
#define NQ_EL  ((size_t)B_SZ * NH * S_LEN * D_HD)   // 3,145,728 per tensor
#define EST    2056                                  // ebuf row stride (bf16)

typedef __attribute__((ext_vector_type(8))) __bf16 bf16x8;
typedef __attribute__((ext_vector_type(4))) __bf16 bf16x4;
typedef __attribute__((ext_vector_type(4))) float  f32x4;
typedef __attribute__((ext_vector_type(4))) unsigned u32x4;

// ---------------- mask layout detection --------------------------------------
__device__ __forceinline__ int detect_mask_mode64(const void* mask) {
  const int lane = threadIdx.x & 63;
  unsigned v = ((const unsigned*)mask)[lane];
  if (__ballot(v <= 1u) == ~0ull) return 0;
  if (__ballot(v == 0u || v == 0x3f800000u) == ~0ull) return 2;
  unsigned h0 = v & 0xFFFFu, h1 = v >> 16;
  bool okb = (h0 == 0u || h0 == 0x3f80u) && (h1 == 0u || h1 == 0x3f80u);
  if (__ballot(okb) == ~0ull) return 3;
  return 1;
}

__device__ __forceinline__ bool mask_at(const void* mask, int mode, size_t idx) {
  if (mode == 0) return ((const int*)mask)[idx] != 0;
  if (mode == 1) return ((const unsigned char*)mask)[idx] != 0;
  if (mode == 2) return ((const float*)mask)[idx] != 0.0f;
  return ((const unsigned short*)mask)[idx] != 0;
}

// ---------------- fused prep: bits + Q/K convert + V transpose ---------------
__global__ __launch_bounds__(256)
void prep_kernel(const float* __restrict__ Q, const float* __restrict__ K,
                 const float* __restrict__ V, const void* __restrict__ mask,
                 unsigned* __restrict__ bits, __bf16* __restrict__ Qb,
                 __bf16* __restrict__ Kb, __bf16* __restrict__ VT) {
  const int blk = blockIdx.x;
  const int tid = threadIdx.x;
  if (blk < 512) {
    const int mode = detect_mask_mode64(mask);
    const int lane = tid & 63;
#pragma unroll 4
    for (int i = 0; i < 64; ++i) {
      const size_t idx = ((size_t)blk * 64 + i) * 256 + tid;
      const unsigned long long bal = __ballot(mask_at(mask, mode, idx));
      if (lane == 0)       bits[idx >> 5] = (unsigned)bal;
      else if (lane == 32) bits[idx >> 5] = (unsigned)(bal >> 32);
    }
  } else if (blk < 1536) {
    const bool isq = blk < 1024;
    const float* src = isq ? Q : K;
    __bf16* dst = isq ? Qb : Kb;
    const float scale = isq ? 0.125f : 1.0f;
    const size_t base = (size_t)(blk & 511) * 256 + tid;
#pragma unroll
    for (int i = 0; i < 6; ++i) {        // 512*256*6 = 786,432 vec4
      const size_t li = base + (size_t)i * 512 * 256;
      float4 a = ((const float4*)src)[li];
      __bf16 o0 = (__bf16)(a.x * scale), o1 = (__bf16)(a.y * scale);
      __bf16 o2 = (__bf16)(a.z * scale), o3 = (__bf16)(a.w * scale);
      ((ushort4*)dst)[li] = (ushort4){
          __builtin_bit_cast(unsigned short, o0), __builtin_bit_cast(unsigned short, o1),
          __builtin_bit_cast(unsigned short, o2), __builtin_bit_cast(unsigned short, o3)};
    }
  } else {                               // V transpose (64k x 64d tile)
    __shared__ __align__(16) __bf16 tl[D_HD][72];
    const int t  = blk - 1536;           // 0..767
    const int bh = t >> 5;               // 0..23
    const int k0 = (t & 31) * 64;
#pragma unroll
    for (int i = 0; i < 4; ++i) {
      const int vi = i * 256 + tid;
      const int kk = vi >> 4, dv = (vi & 15) * 4;
      float4 f = *(const float4*)(V + ((size_t)bh * S_LEN + k0 + kk) * D_HD + dv);
      tl[dv + 0][kk] = (__bf16)f.x; tl[dv + 1][kk] = (__bf16)f.y;
      tl[dv + 2][kk] = (__bf16)f.z; tl[dv + 3][kk] = (__bf16)f.w;
    }
    __syncthreads();
#pragma unroll
    for (int half = 0; half < 2; ++half) {
      const int d = half * 32 + (tid >> 3);
      const int kc = (tid & 7) * 8;
      bf16x8 vv = *(const bf16x8*)&tl[d][kc];
      *(bf16x8*)(VT + ((size_t)bh * D_HD + d) * S_LEN + k0 + kc) = vv;
    }
  }
}

// ---------------- typed load helper (fallback path) --------------------------
__device__ __forceinline__ bf16x8 ld8f(const float* p, float scale) {
  const float4 a = *(const float4*)p;
  const float4 b = *(const float4*)(p + 4);
  bf16x8 r;
  r[0] = (__bf16)(a.x * scale); r[1] = (__bf16)(a.y * scale);
  r[2] = (__bf16)(a.z * scale); r[3] = (__bf16)(a.w * scale);
  r[4] = (__bf16)(b.x * scale); r[5] = (__bf16)(b.y * scale);
  r[6] = (__bf16)(b.z * scale); r[7] = (__bf16)(b.w * scale);
  return r;
}

__device__ __forceinline__ float bflo(unsigned u) {
  return __builtin_bit_cast(float, u << 16);
}
__device__ __forceinline__ float bfhi(unsigned u) {
  return __builtin_bit_cast(float, u & 0xFFFF0000u);
}

// ---------------- main attention ---------------------------------------------
// 3072 blocks x 512 thr (8 waves), 8-way split-K, XCD-contiguous remap.
// Phase 1 (once): swapped QK^T, e=exp(s) packed bf16 in registers AND spilled
// to a padded LDS e-buffer [16 rows][EST].
// Phase 2b: LINEAR prob stores — each wave owns 2 whole q-rows and streams
// them front-to-back: one f32x4 store instruction = 1 KB CONTIGUOUS (channel-
// interleaved), vs all prior rounds' 8KB-strided multi-row bursts that funnel
// each instruction into one L2 channel (hotspot hypothesis, r5-r10 ~1.5TB/s).
// Phase 2a: PV from packed-e registers vs VT global fragments (r10-verified).
// Epilogue: csum aliases the e-buffer (barrier-separated), cooperative merge.
__global__ __launch_bounds__(512, 4)
void attn_main(const __bf16* __restrict__ Qb, const __bf16* __restrict__ Kb,
               const __bf16* __restrict__ VT, const unsigned* __restrict__ mbits,
               float* __restrict__ out_ctx)
{
  float* out_p = out_ctx + NQ_EL;

  const int flat = blockIdx.x + blockIdx.y * gridDim.x;    // 0..3071
  const int wf   = (flat & 7) * 384 + (flat >> 3);         // XCD-contiguous
  const int bh   = wf >> 7;              // 0..23
  const int qg   = wf & 127;             // 0..127
  const int b    = bh / NH;

  const int tid  = threadIdx.x;
  const int lane = tid & 63;
  const int w    = tid >> 6;             // 0..7 (k-split)
  const int qbase = qg * 16;
  const int col  = lane & 15;
  const int g    = lane >> 4;
  const int q    = qbase + col;          // this lane's q-row
  const int k0   = w * 256;

  const size_t mbase = ((size_t)b * S_LEN + q) * (S_LEN / 32);
  const size_t khead = (size_t)bh * S_LEN;

  const size_t qoff = (khead + q) * D_HD + g * 8;
  const bf16x8 bq0 = *(const bf16x8*)(Qb + qoff);
  const bf16x8 bq1 = *(const bf16x8*)(Qb + qoff + 32);

  // LDS: e-buffer (phase 2b source), aliased by csum (epilogue) after barrier.
  __shared__ __align__(16) unsigned char shraw[16 * EST * 2];   // 65,792 B
  auto ebuf = (unsigned short (*)[EST])shraw;
  auto csum = (float (*)[16][66])shraw;                         // [8][16][66]
  __shared__ float lsh[8][16];
  __shared__ float linv_s[16];

  // ---------------- Phase 1: QK^T + exp -> registers + LDS ------------------
  unsigned pe[8][4];
  float lsum = 0.f;
#pragma unroll
  for (int c = 0; c < 8; ++c) {
    const int kc = k0 + c * 32;
    const unsigned mw = mbits[mbase + (kc >> 5)];
    float e[8];
#pragma unroll
    for (int sub = 0; sub < 2; ++sub) {
      const int kb = kc + sub * 16;
      const size_t koff = (khead + kb + col) * D_HD + g * 8;
      bf16x8 ak0 = *(const bf16x8*)(Kb + koff);
      bf16x8 ak1 = *(const bf16x8*)(Kb + koff + 32);
      f32x4 acc = {0.f, 0.f, 0.f, 0.f};
      acc = __builtin_amdgcn_mfma_f32_16x16x32_bf16(ak0, bq0, acc, 0, 0, 0);
      acc = __builtin_amdgcn_mfma_f32_16x16x32_bf16(ak1, bq1, acc, 0, 0, 0);
#pragma unroll
      for (int r = 0; r < 4; ++r) {
        const bool msk = (mw >> (sub * 16 + g * 4 + r)) & 1;
        float ev = msk ? 0.f : __expf(acc[r]);
        e[sub * 4 + r] = ev;
        lsum += ev;
      }
    }
#pragma unroll
    for (int j = 0; j < 4; ++j) {
      unsigned lo = __builtin_bit_cast(unsigned short, (__bf16)e[2 * j]);
      unsigned hi = __builtin_bit_cast(unsigned short, (__bf16)e[2 * j + 1]);
      pe[c][j] = (hi << 16) | lo;
    }
    // spill to e-buffer: 4 consecutive bf16 at k=kc+g*4 and kc+16+g*4
    unsigned long long v01 = (unsigned long long)pe[c][0] |
                             ((unsigned long long)pe[c][1] << 32);
    unsigned long long v23 = (unsigned long long)pe[c][2] |
                             ((unsigned long long)pe[c][3] << 32);
    *(unsigned long long*)&ebuf[col][kc + g * 4]      = v01;
    *(unsigned long long*)&ebuf[col][kc + 16 + g * 4] = v23;
  }
  lsum += __shfl_xor(lsum, 16);
  lsum += __shfl_xor(lsum, 32);
  if (lane < 16) lsh[w][col] = lsum;
  __syncthreads();                       // barrier 1: ebuf + lsh complete

  {                                      // epilogue normalizer (own row)
    float tot = 0.f;
#pragma unroll
    for (int w8 = 0; w8 < 8; ++w8) tot += lsh[w8][col];
    if (w == 0 && lane < 16) linv_s[col] = 1.0f / tot;
  }

  // ---------------- Phase 2b: LINEAR prob store streams ---------------------
  // Wave w owns rows 2w, 2w+1. One store instr = 64 lanes x 16B = 1KB contig.
#pragma unroll
  for (int j = 0; j < 2; ++j) {
    const int rr = w * 2 + j;
    float tot = 0.f;
#pragma unroll
    for (int w8 = 0; w8 < 8; ++w8) tot += lsh[w8][rr];
    const float lv = 1.0f / tot;
    float* prow = out_p + (size_t)bh * S_LEN * S_LEN +
                  (size_t)(qbase + rr) * S_LEN;
#pragma unroll
    for (int i = 0; i < 8; ++i) {
      const int k = i * 256 + lane * 4;
      unsigned long long v = *(const unsigned long long*)&ebuf[rr][k];
      const unsigned u0 = (unsigned)v, u1 = (unsigned)(v >> 32);
      f32x4 st = {bflo(u0) * lv, bfhi(u0) * lv, bflo(u1) * lv, bfhi(u1) * lv};
      *(f32x4*)(prow + k) = st;
    }
  }

  // ---------------- Phase 2a: PV (register P, global VT) --------------------
  f32x4 cacc[4];
#pragma unroll
  for (int dt = 0; dt < 4; dt++) cacc[dt] = (f32x4){0.f, 0.f, 0.f, 0.f};
  const __bf16* vbase = VT + (size_t)bh * D_HD * S_LEN;   // [d][k]

#pragma unroll
  for (int c = 0; c < 8; ++c) {
    const int kc = k0 + c * 32;
    u32x4 w4 = {pe[c][0], pe[c][1], pe[c][2], pe[c][3]};
    bf16x8 pa = __builtin_bit_cast(bf16x8, w4);
#pragma unroll
    for (int dt = 0; dt < 4; dt++) {
      const __bf16* vrow = vbase + (size_t)(dt * 16 + col) * S_LEN + kc;
      bf16x4 lo = *(const bf16x4*)(vrow + g * 4);
      bf16x4 hi = *(const bf16x4*)(vrow + 16 + g * 4);
      bf16x8 vf = __builtin_shufflevector(lo, hi, 0, 1, 2, 3, 4, 5, 6, 7);
      cacc[dt] = __builtin_amdgcn_mfma_f32_16x16x32_bf16(pa, vf, cacc[dt], 0, 0, 0);
    }
  }

  // ---------------- epilogue: cooperative 8-way merge (csum aliases ebuf) ---
  __syncthreads();                       // barrier 2: all ebuf reads done
#pragma unroll
  for (int dt = 0; dt < 4; dt++)
#pragma unroll
    for (int r = 0; r < 4; r++)
      csum[w][g * 4 + r][dt * 16 + col] = cacc[dt][r];
  __syncthreads();                       // barrier 3
  {
    const int qo = tid >> 5;             // 0..15
    const int d0 = (tid * 2) & 63;       // even
    float s0 = 0.f, s1 = 0.f;
#pragma unroll
    for (int w8 = 0; w8 < 8; ++w8) {
      s0 += csum[w8][qo][d0];
      s1 += csum[w8][qo][d0 + 1];
    }
    const float lv = linv_s[qo];
    float2 o = {s0 * lv, s1 * lv};
    *(float2*)(out_ctx + ((size_t)bh * S_LEN + qbase + qo) * D_HD + d0) = o;
  }
}

// ---------------- fallback (round-6 proven kernel, f32 direct) ---------------
template<bool USE_BITS>
__global__ __launch_bounds__(512)
void attn_fb(const float* __restrict__ Qg, const float* __restrict__ Kg,
             const float* __restrict__ Vg, const void* __restrict__ mask,
             const unsigned* __restrict__ mbits, float* __restrict__ out_ctx)
{
  float* out_p = out_ctx + NQ_EL;
  const int flat = blockIdx.x + blockIdx.y * gridDim.x;
  const int wf   = (flat & 7) * 96 + (flat >> 3);
  const int qt = wf & 31, bh = wf >> 5, b = bh / NH;
  const int tid = threadIdx.x, lane = tid & 63, w = tid >> 6;
  const int qw = w & 3, kh = w >> 2;
  const int qbase = qt * 64 + qw * 16;
  const int col = lane & 15, g = lane >> 4;
  const int q = qbase + col;
  const int k0 = kh * (S_LEN / 2);
  int mmode = 0;
  if constexpr (!USE_BITS) mmode = detect_mask_mode64(mask);
  const size_t mrow  = (size_t)b * S_LEN * S_LEN;
  const size_t mbase = ((size_t)b * S_LEN + q) * (S_LEN / 32);
  const size_t qoff = ((size_t)bh * S_LEN + q) * D_HD + g * 8;
  const bf16x8 bq0 = ld8f(Qg + qoff, 0.125f);
  const bf16x8 bq1 = ld8f(Qg + qoff + 32, 0.125f);

  float lsum = 0.f;
  for (int kc = k0; kc < k0 + S_LEN / 2; kc += 32) {
    unsigned mw = 0;
    if constexpr (USE_BITS) mw = mbits[mbase + (kc >> 5)];
#pragma unroll
    for (int sub = 0; sub < 2; ++sub) {
      const int kb = kc + sub * 16;
      const size_t koff = ((size_t)bh * S_LEN + kb + col) * D_HD + g * 8;
      bf16x8 ak0 = ld8f(Kg + koff, 1.0f);
      bf16x8 ak1 = ld8f(Kg + koff + 32, 1.0f);
      f32x4 acc = {0.f, 0.f, 0.f, 0.f};
      acc = __builtin_amdgcn_mfma_f32_16x16x32_bf16(ak0, bq0, acc, 0, 0, 0);
      acc = __builtin_amdgcn_mfma_f32_16x16x32_bf16(ak1, bq1, acc, 0, 0, 0);
#pragma unroll
      for (int r = 0; r < 4; ++r) {
        bool msk;
        if constexpr (USE_BITS) msk = (mw >> (sub * 16 + g * 4 + r)) & 1;
        else msk = mask_at(mask, mmode, mrow + (size_t)q * S_LEN + kb + g * 4 + r);
        lsum += msk ? 0.f : __expf(acc[r]);
      }
    }
  }
  lsum += __shfl_xor(lsum, 16);
  lsum += __shfl_xor(lsum, 32);
  __shared__ float lsh[8][16];
  __shared__ float csum[4][16][66];
  if (lane < 16) lsh[w][col] = lsum;
  __syncthreads();
  const float inv_l = 1.0f / (lsum + lsh[w ^ 4][col]);

  f32x4 cacc[4];
#pragma unroll
  for (int dt = 0; dt < 4; dt++) cacc[dt] = (f32x4){0.f, 0.f, 0.f, 0.f};
  float* prow = out_p + (size_t)bh * S_LEN * S_LEN + (size_t)q * S_LEN;

  for (int it = 0; it < S_LEN / 64; ++it) {
    const int kc = k0 + it * 32;
    unsigned mw = 0;
    if constexpr (USE_BITS) mw = mbits[mbase + (kc >> 5)];
    float p[8];
#pragma unroll
    for (int sub = 0; sub < 2; ++sub) {
      const int kb = kc + sub * 16;
      const size_t koff = ((size_t)bh * S_LEN + kb + col) * D_HD + g * 8;
      bf16x8 ak0 = ld8f(Kg + koff, 1.0f);
      bf16x8 ak1 = ld8f(Kg + koff + 32, 1.0f);
      f32x4 acc = {0.f, 0.f, 0.f, 0.f};
      acc = __builtin_amdgcn_mfma_f32_16x16x32_bf16(ak0, bq0, acc, 0, 0, 0);
      acc = __builtin_amdgcn_mfma_f32_16x16x32_bf16(ak1, bq1, acc, 0, 0, 0);
#pragma unroll
      for (int r = 0; r < 4; ++r) {
        bool msk;
        if constexpr (USE_BITS) msk = (mw >> (sub * 16 + g * 4 + r)) & 1;
        else msk = mask_at(mask, mmode, mrow + (size_t)q * S_LEN + kb + g * 4 + r);
        p[sub * 4 + r] = msk ? 0.f : __expf(acc[r]) * inv_l;
      }
      float4 st = {p[sub * 4 + 0], p[sub * 4 + 1], p[sub * 4 + 2], p[sub * 4 + 3]};
      *(float4*)(prow + kb + g * 4) = st;
    }
    bf16x8 pa;
#pragma unroll
    for (int e = 0; e < 8; e++) pa[e] = (__bf16)p[e];
#pragma unroll
    for (int dt = 0; dt < 4; dt++) {
      bf16x8 vf;
#pragma unroll
      for (int e = 0; e < 8; e++) {
        const int kidx = kc + (e >> 2) * 16 + g * 4 + (e & 3);
        vf[e] = (__bf16)Vg[((size_t)bh * S_LEN + kidx) * D_HD + dt * 16 + col];
      }
      cacc[dt] = __builtin_amdgcn_mfma_f32_16x16x32_bf16(pa, vf, cacc[dt], 0, 0, 0);
    }
  }
  if (kh == 1) {
#pragma unroll
    for (int dt = 0; dt < 4; dt++)
#pragma unroll
      for (int r = 0; r < 4; r++)
        csum[qw][g * 4 + r][dt * 16 + col] = cacc[dt][r];
  }
  __syncthreads();
  if (kh == 0) {
#pragma unroll
    for (int dt = 0; dt < 4; dt++)
#pragma unroll
      for (int r = 0; r < 4; r++)
        out_ctx[((size_t)bh * S_LEN + qbase + g * 4 + r) * D_HD + dt * 16 + col] =
            cacc[dt][r] + csum[qw][g * 4 + r][dt * 16 + col];
  }
}

__global__ __launch_bounds__(256)
void build_bits_kernel(const void* __restrict__ mask, unsigned* __restrict__ bits) {
  const int mode = detect_mask_mode64(mask);
  const size_t i = (size_t)blockIdx.x * 256 + threadIdx.x;
  const unsigned long long bal = __ballot(mask_at(mask, mode, i));
  const int lane = threadIdx.x & 63;
  if (lane == 0)       bits[i >> 5] = (unsigned)bal;
  else if (lane == 32) bits[i >> 5] = (unsigned)(bal >> 32);
}

extern "C" void kernel_launch(void* const* d_in, const int* in_sizes, int n_in,
                              void* d_out, int out_size, void* d_ws, size_t ws_size,
                              hipStream_t stream) {
  const float* Q = (const float*)d_in[0];
  const float* K = (const float*)d_in[1];
  const float* V = (const float*)d_in[2];
  const void* mask = d_in[3];
  float* out = (float*)d_out;

  const size_t mask_elems = (size_t)B_SZ * S_LEN * S_LEN;   // 8,388,608
  const size_t off_bits = 256;
  const size_t off_q  = off_bits + mask_elems / 8;          // +1 MB
  const size_t off_k  = off_q + NQ_EL * 2;
  const size_t off_vt = off_k + NQ_EL * 2;
  const size_t need   = off_vt + NQ_EL * 2;                 // ~19.9 MB

  if (ws_size >= need) {
    unsigned* bits = (unsigned*)((char*)d_ws + off_bits);
    __bf16* Qb = (__bf16*)((char*)d_ws + off_q);
    __bf16* Kb = (__bf16*)((char*)d_ws + off_k);
    __bf16* VT = (__bf16*)((char*)d_ws + off_vt);
    prep_kernel<<<2304, 256, 0, stream>>>(Q, K, V, mask, bits, Qb, Kb, VT);
    dim3 grid(128, 24);                                     // 3072 blocks
    attn_main<<<grid, 512, 0, stream>>>(Qb, Kb, VT, bits, out);
  } else if (ws_size >= off_q) {
    unsigned* bits = (unsigned*)((char*)d_ws + off_bits);
    build_bits_kernel<<<(unsigned)(mask_elems / 256), 256, 0, stream>>>(mask, bits);
    dim3 gfb(S_LEN / 64, B_SZ * NH);
    attn_fb<true><<<gfb, 512, 0, stream>>>(Q, K, V, mask, bits, out);
  } else {
    dim3 gfb(S_LEN / 64, B_SZ * NH);
    attn_fb<false><<<gfb, 512, 0, stream>>>(Q, K, V, mask, nullptr, out);
  }
}

// Round 12
// 313.555 us; speedup vs baseline: 1.1085x; 1.1085x over previous
//
#include <hip/hip_runtime.h>
#include <hip/hip_bf16.h>
#include <math.h>

// Problem: B=2, H=12, S=2048, D=64. Device I/O: f32 inputs, f32 outputs.
#define B_SZ   2
#define NH     12
#define S_LEN  2048
#define D_HD   64
#define NQ_EL  ((size_t)B_SZ * NH * S_LEN * D_HD)   // 3,145,728 per tensor

typedef __attribute__((ext_vector_type(8))) __bf16 bf16x8;
typedef __attribute__((ext_vector_type(4))) __bf16 bf16x4;
typedef __attribute__((ext_vector_type(4))) float  f32x4;
typedef __attribute__((ext_vector_type(4))) unsigned u32x4;

// ---------------- mask layout detection --------------------------------------
__device__ __forceinline__ int detect_mask_mode64(const void* mask) {
  const int lane = threadIdx.x & 63;
  unsigned v = ((const unsigned*)mask)[lane];
  if (__ballot(v <= 1u) == ~0ull) return 0;
  if (__ballot(v == 0u || v == 0x3f800000u) == ~0ull) return 2;
  unsigned h0 = v & 0xFFFFu, h1 = v >> 16;
  bool okb = (h0 == 0u || h0 == 0x3f80u) && (h1 == 0u || h1 == 0x3f80u);
  if (__ballot(okb) == ~0ull) return 3;
  return 1;
}

__device__ __forceinline__ bool mask_at(const void* mask, int mode, size_t idx) {
  if (mode == 0) return ((const int*)mask)[idx] != 0;
  if (mode == 1) return ((const unsigned char*)mask)[idx] != 0;
  if (mode == 2) return ((const float*)mask)[idx] != 0.0f;
  return ((const unsigned short*)mask)[idx] != 0;
}

// ---------------- fused prep: bits + Q/K convert + V transpose ---------------
__global__ __launch_bounds__(256)
void prep_kernel(const float* __restrict__ Q, const float* __restrict__ K,
                 const float* __restrict__ V, const void* __restrict__ mask,
                 unsigned* __restrict__ bits, __bf16* __restrict__ Qb,
                 __bf16* __restrict__ Kb, __bf16* __restrict__ VT) {
  const int blk = blockIdx.x;
  const int tid = threadIdx.x;
  if (blk < 512) {
    const int mode = detect_mask_mode64(mask);
    const int lane = tid & 63;
#pragma unroll 4
    for (int i = 0; i < 64; ++i) {
      const size_t idx = ((size_t)blk * 64 + i) * 256 + tid;
      const unsigned long long bal = __ballot(mask_at(mask, mode, idx));
      if (lane == 0)       bits[idx >> 5] = (unsigned)bal;
      else if (lane == 32) bits[idx >> 5] = (unsigned)(bal >> 32);
    }
  } else if (blk < 1536) {
    const bool isq = blk < 1024;
    const float* src = isq ? Q : K;
    __bf16* dst = isq ? Qb : Kb;
    const float scale = isq ? 0.125f : 1.0f;
    const size_t base = (size_t)(blk & 511) * 256 + tid;
#pragma unroll
    for (int i = 0; i < 6; ++i) {        // 512*256*6 = 786,432 vec4
      const size_t li = base + (size_t)i * 512 * 256;
      float4 a = ((const float4*)src)[li];
      __bf16 o0 = (__bf16)(a.x * scale), o1 = (__bf16)(a.y * scale);
      __bf16 o2 = (__bf16)(a.z * scale), o3 = (__bf16)(a.w * scale);
      ((ushort4*)dst)[li] = (ushort4){
          __builtin_bit_cast(unsigned short, o0), __builtin_bit_cast(unsigned short, o1),
          __builtin_bit_cast(unsigned short, o2), __builtin_bit_cast(unsigned short, o3)};
    }
  } else {                               // V transpose (64k x 64d tile)
    __shared__ __align__(16) __bf16 tl[D_HD][72];
    const int t  = blk - 1536;           // 0..767
    const int bh = t >> 5;               // 0..23
    const int k0 = (t & 31) * 64;
#pragma unroll
    for (int i = 0; i < 4; ++i) {
      const int vi = i * 256 + tid;
      const int kk = vi >> 4, dv = (vi & 15) * 4;
      float4 f = *(const float4*)(V + ((size_t)bh * S_LEN + k0 + kk) * D_HD + dv);
      tl[dv + 0][kk] = (__bf16)f.x; tl[dv + 1][kk] = (__bf16)f.y;
      tl[dv + 2][kk] = (__bf16)f.z; tl[dv + 3][kk] = (__bf16)f.w;
    }
    __syncthreads();
#pragma unroll
    for (int half = 0; half < 2; ++half) {
      const int d = half * 32 + (tid >> 3);
      const int kc = (tid & 7) * 8;
      bf16x8 vv = *(const bf16x8*)&tl[d][kc];
      *(bf16x8*)(VT + ((size_t)bh * D_HD + d) * S_LEN + k0 + kc) = vv;
    }
  }
}

// ---------------- typed load helper (fallback path) --------------------------
__device__ __forceinline__ bf16x8 ld8f(const float* p, float scale) {
  const float4 a = *(const float4*)p;
  const float4 b = *(const float4*)(p + 4);
  bf16x8 r;
  r[0] = (__bf16)(a.x * scale); r[1] = (__bf16)(a.y * scale);
  r[2] = (__bf16)(a.z * scale); r[3] = (__bf16)(a.w * scale);
  r[4] = (__bf16)(b.x * scale); r[5] = (__bf16)(b.y * scale);
  r[6] = (__bf16)(b.z * scale); r[7] = (__bf16)(b.w * scale);
  return r;
}

__device__ __forceinline__ float bflo(unsigned u) {
  return __builtin_bit_cast(float, u << 16);
}
__device__ __forceinline__ float bfhi(unsigned u) {
  return __builtin_bit_cast(float, u & 0xFFFF0000u);
}

// ---------------- main attention: single QK^T, P-in-registers ----------------
// EXACTLY the round-10 kernel with ONE change: the gathered full-line prob
// stores are NONTEMPORAL. Evidence: r9 (nt, half-lines) sustained 1.79 TB/s
// raw write throughput (best of all rounds) but paid +141 MB RMW amplification;
// r10 (cached, full lines) fixed bytes but fell back to 1.4 TB/s. Full 128B
// lines + nt should combine r9's throughput with r10's byte count, and stop
// the 403 MB write stream from thrashing L2/LLC (read sets stay resident).
__global__ __launch_bounds__(512, 4)
void attn_main(const __bf16* __restrict__ Qb, const __bf16* __restrict__ Kb,
               const __bf16* __restrict__ VT, const unsigned* __restrict__ mbits,
               float* __restrict__ out_ctx)
{
  float* out_p = out_ctx + NQ_EL;

  const int flat = blockIdx.x + blockIdx.y * gridDim.x;    // 0..3071
  const int wf   = (flat & 7) * 384 + (flat >> 3);         // XCD-contiguous
  const int bh   = wf >> 7;              // 0..23
  const int qg   = wf & 127;             // 0..127
  const int b    = bh / NH;

  const int tid  = threadIdx.x;
  const int lane = tid & 63;
  const int w    = tid >> 6;             // 0..7 (k-split)
  const int qbase = qg * 16;
  const int col  = lane & 15;
  const int g    = lane >> 4;
  const int q    = qbase + col;          // this lane's q-row
  const int k0   = w * 256;

  const size_t mbase = ((size_t)b * S_LEN + q) * (S_LEN / 32);
  const size_t khead = (size_t)bh * S_LEN;

  const size_t qoff = (khead + q) * D_HD + g * 8;
  const bf16x8 bq0 = *(const bf16x8*)(Qb + qoff);
  const bf16x8 bq1 = *(const bf16x8*)(Qb + qoff + 32);

  __shared__ float lsh[8][16];
  __shared__ float linv_s[16];
  __shared__ float csum[8][16][66];

  // ---------------- Phase 1: QK^T + exp, depth-2 prefetch -------------------
  unsigned pe[8][4];                     // [chunk][pair] bf16x2, static indices
  float lsum = 0.f;

  bf16x8 nk0a, nk0b, nk1a, nk1b;         // prefetched K fragments (chunk c+1)
  {
    const size_t koff0 = (khead + k0 + col) * D_HD + g * 8;
    const size_t koff1 = (khead + k0 + 16 + col) * D_HD + g * 8;
    nk0a = *(const bf16x8*)(Kb + koff0);
    nk0b = *(const bf16x8*)(Kb + koff0 + 32);
    nk1a = *(const bf16x8*)(Kb + koff1);
    nk1b = *(const bf16x8*)(Kb + koff1 + 32);
  }
  unsigned nmw = mbits[mbase + (k0 >> 5)];

#pragma unroll
  for (int c = 0; c < 8; ++c) {
    const bf16x8 k0a = nk0a, k0b = nk0b, k1a = nk1a, k1b = nk1b;
    const unsigned mw = nmw;
    if (c < 7) {                         // prefetch next chunk
      const int kn = k0 + (c + 1) * 32;
      const size_t koff0 = (khead + kn + col) * D_HD + g * 8;
      const size_t koff1 = (khead + kn + 16 + col) * D_HD + g * 8;
      nk0a = *(const bf16x8*)(Kb + koff0);
      nk0b = *(const bf16x8*)(Kb + koff0 + 32);
      nk1a = *(const bf16x8*)(Kb + koff1);
      nk1b = *(const bf16x8*)(Kb + koff1 + 32);
      nmw = mbits[mbase + (kn >> 5)];
    }
    float e[8];
    {
      f32x4 acc = {0.f, 0.f, 0.f, 0.f};
      acc = __builtin_amdgcn_mfma_f32_16x16x32_bf16(k0a, bq0, acc, 0, 0, 0);
      acc = __builtin_amdgcn_mfma_f32_16x16x32_bf16(k0b, bq1, acc, 0, 0, 0);
#pragma unroll
      for (int r = 0; r < 4; ++r) {
        const bool msk = (mw >> (g * 4 + r)) & 1;
        e[r] = msk ? 0.f : __expf(acc[r]);
        lsum += e[r];
      }
    }
    {
      f32x4 acc = {0.f, 0.f, 0.f, 0.f};
      acc = __builtin_amdgcn_mfma_f32_16x16x32_bf16(k1a, bq0, acc, 0, 0, 0);
      acc = __builtin_amdgcn_mfma_f32_16x16x32_bf16(k1b, bq1, acc, 0, 0, 0);
#pragma unroll
      for (int r = 0; r < 4; ++r) {
        const bool msk = (mw >> (16 + g * 4 + r)) & 1;
        e[4 + r] = msk ? 0.f : __expf(acc[r]);
        lsum += e[4 + r];
      }
    }
#pragma unroll
    for (int j = 0; j < 4; ++j) {
      unsigned lo = __builtin_bit_cast(unsigned short, (__bf16)e[2 * j]);
      unsigned hi = __builtin_bit_cast(unsigned short, (__bf16)e[2 * j + 1]);
      pe[c][j] = (hi << 16) | lo;
    }
  }
  lsum += __shfl_xor(lsum, 16);
  lsum += __shfl_xor(lsum, 32);
  if (lane < 16) lsh[w][col] = lsum;
  __syncthreads();                       // barrier 1
  // epilogue normalizer (own row), published for the merge step
  {
    float tot = 0.f;
#pragma unroll
    for (int w8 = 0; w8 < 8; ++w8) tot += lsh[w8][col];
    if (w == 0 && lane < 16) linv_s[col] = 1.0f / tot;
  }
  // store-path normalizers: rows (lane>>3) and 8+(lane>>3)
  const int Lr = lane >> 3;              // row-in-group 0..7
  const int u  = lane & 7;               // 32-float chunk position
  float linv_t[2];
#pragma unroll
  for (int t = 0; t < 2; ++t) {
    float tot = 0.f;
#pragma unroll
    for (int w8 = 0; w8 < 8; ++w8) tot += lsh[w8][t * 8 + Lr];
    linv_t[t] = 1.0f / tot;
  }
  const int subg = u >> 2;               // which pe pair-half this lane stores

  // ---------------- Phase 2: full-line NONTEMPORAL prob stores + PV ---------
  f32x4 cacc[4];
#pragma unroll
  for (int dt = 0; dt < 4; dt++) cacc[dt] = (f32x4){0.f, 0.f, 0.f, 0.f};

  float* pblk = out_p + (size_t)bh * S_LEN * S_LEN + (size_t)qbase * S_LEN + k0;
  const __bf16* vbase = VT + (size_t)bh * D_HD * S_LEN;   // [d][k]

#pragma unroll
  for (int c = 0; c < 8; ++c) {
    const int kc = k0 + c * 32;
    // V^T fragments (independent -> issue early)
    bf16x8 vf[4];
#pragma unroll
    for (int dt = 0; dt < 4; dt++) {
      const __bf16* vrow = vbase + (size_t)(dt * 16 + col) * S_LEN + kc;
      bf16x4 lo = *(const bf16x4*)(vrow + g * 4);
      bf16x4 hi = *(const bf16x4*)(vrow + 16 + g * 4);
      vf[dt] = __builtin_shufflevector(lo, hi, 0, 1, 2, 3, 4, 5, 6, 7);
    }
    // prob stores: gather so each instruction writes 8 rows x 128B FULL lines,
    // nontemporal (full coverage -> no RMW amplification; bypasses LLC).
#pragma unroll
    for (int t = 0; t < 2; ++t) {
      const int src = 16 * (u & 3) + t * 8 + Lr;
      unsigned a0 = (unsigned)__shfl((int)pe[c][0], src);
      unsigned a1 = (unsigned)__shfl((int)pe[c][1], src);
      unsigned a2 = (unsigned)__shfl((int)pe[c][2], src);
      unsigned a3 = (unsigned)__shfl((int)pe[c][3], src);
      const unsigned lo = subg ? a2 : a0;
      const unsigned hi = subg ? a3 : a1;
      const float lv = linv_t[t];
      f32x4 st = {bflo(lo) * lv, bfhi(lo) * lv, bflo(hi) * lv, bfhi(hi) * lv};
      __builtin_nontemporal_store(
          st, (f32x4*)(pblk + (size_t)(t * 8 + Lr) * S_LEN + c * 32 + u * 4));
    }
    // PV: packed e IS the A-frag (k-order sigma matches vf)
    u32x4 w4 = {pe[c][0], pe[c][1], pe[c][2], pe[c][3]};
    bf16x8 pa = __builtin_bit_cast(bf16x8, w4);
#pragma unroll
    for (int dt = 0; dt < 4; dt++)
      cacc[dt] = __builtin_amdgcn_mfma_f32_16x16x32_bf16(pa, vf[dt], cacc[dt], 0, 0, 0);
  }

  // ---------------- epilogue: cooperative 8-way merge -----------------------
#pragma unroll
  for (int dt = 0; dt < 4; dt++)
#pragma unroll
    for (int r = 0; r < 4; r++)
      csum[w][g * 4 + r][dt * 16 + col] = cacc[dt][r];
  __syncthreads();                       // barrier 2
  {
    const int qo = tid >> 5;             // 0..15
    const int d0 = (tid * 2) & 63;       // even
    float s0 = 0.f, s1 = 0.f;
#pragma unroll
    for (int w8 = 0; w8 < 8; ++w8) {
      s0 += csum[w8][qo][d0];
      s1 += csum[w8][qo][d0 + 1];
    }
    const float lv = linv_s[qo];
    float2 o = {s0 * lv, s1 * lv};
    *(float2*)(out_ctx + ((size_t)bh * S_LEN + qbase + qo) * D_HD + d0) = o;
  }
}

// ---------------- fallback (round-6 proven kernel, f32 direct) ---------------
template<bool USE_BITS>
__global__ __launch_bounds__(512)
void attn_fb(const float* __restrict__ Qg, const float* __restrict__ Kg,
             const float* __restrict__ Vg, const void* __restrict__ mask,
             const unsigned* __restrict__ mbits, float* __restrict__ out_ctx)
{
  float* out_p = out_ctx + NQ_EL;
  const int flat = blockIdx.x + blockIdx.y * gridDim.x;
  const int wf   = (flat & 7) * 96 + (flat >> 3);
  const int qt = wf & 31, bh = wf >> 5, b = bh / NH;
  const int tid = threadIdx.x, lane = tid & 63, w = tid >> 6;
  const int qw = w & 3, kh = w >> 2;
  const int qbase = qt * 64 + qw * 16;
  const int col = lane & 15, g = lane >> 4;
  const int q = qbase + col;
  const int k0 = kh * (S_LEN / 2);
  int mmode = 0;
  if constexpr (!USE_BITS) mmode = detect_mask_mode64(mask);
  const size_t mrow  = (size_t)b * S_LEN * S_LEN;
  const size_t mbase = ((size_t)b * S_LEN + q) * (S_LEN / 32);
  const size_t qoff = ((size_t)bh * S_LEN + q) * D_HD + g * 8;
  const bf16x8 bq0 = ld8f(Qg + qoff, 0.125f);
  const bf16x8 bq1 = ld8f(Qg + qoff + 32, 0.125f);

  float lsum = 0.f;
  for (int kc = k0; kc < k0 + S_LEN / 2; kc += 32) {
    unsigned mw = 0;
    if constexpr (USE_BITS) mw = mbits[mbase + (kc >> 5)];
#pragma unroll
    for (int sub = 0; sub < 2; ++sub) {
      const int kb = kc + sub * 16;
      const size_t koff = ((size_t)bh * S_LEN + kb + col) * D_HD + g * 8;
      bf16x8 ak0 = ld8f(Kg + koff, 1.0f);
      bf16x8 ak1 = ld8f(Kg + koff + 32, 1.0f);
      f32x4 acc = {0.f, 0.f, 0.f, 0.f};
      acc = __builtin_amdgcn_mfma_f32_16x16x32_bf16(ak0, bq0, acc, 0, 0, 0);
      acc = __builtin_amdgcn_mfma_f32_16x16x32_bf16(ak1, bq1, acc, 0, 0, 0);
#pragma unroll
      for (int r = 0; r < 4; ++r) {
        bool msk;
        if constexpr (USE_BITS) msk = (mw >> (sub * 16 + g * 4 + r)) & 1;
        else msk = mask_at(mask, mmode, mrow + (size_t)q * S_LEN + kb + g * 4 + r);
        lsum += msk ? 0.f : __expf(acc[r]);
      }
    }
  }
  lsum += __shfl_xor(lsum, 16);
  lsum += __shfl_xor(lsum, 32);
  __shared__ float lsh[8][16];
  __shared__ float csum[4][16][66];
  if (lane < 16) lsh[w][col] = lsum;
  __syncthreads();
  const float inv_l = 1.0f / (lsum + lsh[w ^ 4][col]);

  f32x4 cacc[4];
#pragma unroll
  for (int dt = 0; dt < 4; dt++) cacc[dt] = (f32x4){0.f, 0.f, 0.f, 0.f};
  float* prow = out_p + (size_t)bh * S_LEN * S_LEN + (size_t)q * S_LEN;

  for (int it = 0; it < S_LEN / 64; ++it) {
    const int kc = k0 + it * 32;
    unsigned mw = 0;
    if constexpr (USE_BITS) mw = mbits[mbase + (kc >> 5)];
    float p[8];
#pragma unroll
    for (int sub = 0; sub < 2; ++sub) {
      const int kb = kc + sub * 16;
      const size_t koff = ((size_t)bh * S_LEN + kb + col) * D_HD + g * 8;
      bf16x8 ak0 = ld8f(Kg + koff, 1.0f);
      bf16x8 ak1 = ld8f(Kg + koff + 32, 1.0f);
      f32x4 acc = {0.f, 0.f, 0.f, 0.f};
      acc = __builtin_amdgcn_mfma_f32_16x16x32_bf16(ak0, bq0, acc, 0, 0, 0);
      acc = __builtin_amdgcn_mfma_f32_16x16x32_bf16(ak1, bq1, acc, 0, 0, 0);
#pragma unroll
      for (int r = 0; r < 4; ++r) {
        bool msk;
        if constexpr (USE_BITS) msk = (mw >> (sub * 16 + g * 4 + r)) & 1;
        else msk = mask_at(mask, mmode, mrow + (size_t)q * S_LEN + kb + g * 4 + r);
        p[sub * 4 + r] = msk ? 0.f : __expf(acc[r]) * inv_l;
      }
      float4 st = {p[sub * 4 + 0], p[sub * 4 + 1], p[sub * 4 + 2], p[sub * 4 + 3]};
      *(float4*)(prow + kb + g * 4) = st;
    }
    bf16x8 pa;
#pragma unroll
    for (int e = 0; e < 8; e++) pa[e] = (__bf16)p[e];
#pragma unroll
    for (int dt = 0; dt < 4; dt++) {
      bf16x8 vf;
#pragma unroll
      for (int e = 0; e < 8; e++) {
        const int kidx = kc + (e >> 2) * 16 + g * 4 + (e & 3);
        vf[e] = (__bf16)Vg[((size_t)bh * S_LEN + kidx) * D_HD + dt * 16 + col];
      }
      cacc[dt] = __builtin_amdgcn_mfma_f32_16x16x32_bf16(pa, vf, cacc[dt], 0, 0, 0);
    }
  }
  if (kh == 1) {
#pragma unroll
    for (int dt = 0; dt < 4; dt++)
#pragma unroll
      for (int r = 0; r < 4; r++)
        csum[qw][g * 4 + r][dt * 16 + col] = cacc[dt][r];
  }
  __syncthreads();
  if (kh == 0) {
#pragma unroll
    for (int dt = 0; dt < 4; dt++)
#pragma unroll
      for (int r = 0; r < 4; r++)
        out_ctx[((size_t)bh * S_LEN + qbase + g * 4 + r) * D_HD + dt * 16 + col] =
            cacc[dt][r] + csum[qw][g * 4 + r][dt * 16 + col];
  }
}

__global__ __launch_bounds__(256)
void build_bits_kernel(const void* __restrict__ mask, unsigned* __restrict__ bits) {
  const int mode = detect_mask_mode64(mask);
  const size_t i = (size_t)blockIdx.x * 256 + threadIdx.x;
  const unsigned long long bal = __ballot(mask_at(mask, mode, i));
  const int lane = threadIdx.x & 63;
  if (lane == 0)       bits[i >> 5] = (unsigned)bal;
  else if (lane == 32) bits[i >> 5] = (unsigned)(bal >> 32);
}

extern "C" void kernel_launch(void* const* d_in, const int* in_sizes, int n_in,
                              void* d_out, int out_size, void* d_ws, size_t ws_size,
                              hipStream_t stream) {
  const float* Q = (const float*)d_in[0];
  const float* K = (const float*)d_in[1];
  const float* V = (const float*)d_in[2];
  const void* mask = d_in[3];
  float* out = (float*)d_out;

  const size_t mask_elems = (size_t)B_SZ * S_LEN * S_LEN;   // 8,388,608
  const size_t off_bits = 256;
  const size_t off_q  = off_bits + mask_elems / 8;          // +1 MB
  const size_t off_k  = off_q + NQ_EL * 2;
  const size_t off_vt = off_k + NQ_EL * 2;
  const size_t need   = off_vt + NQ_EL * 2;                 // ~19.9 MB

  if (ws_size >= need) {
    unsigned* bits = (unsigned*)((char*)d_ws + off_bits);
    __bf16* Qb = (__bf16*)((char*)d_ws + off_q);
    __bf16* Kb = (__bf16*)((char*)d_ws + off_k);
    __bf16* VT = (__bf16*)((char*)d_ws + off_vt);
    prep_kernel<<<2304, 256, 0, stream>>>(Q, K, V, mask, bits, Qb, Kb, VT);
    dim3 grid(128, 24);                                     // 3072 blocks
    attn_main<<<grid, 512, 0, stream>>>(Qb, Kb, VT, bits, out);
  } else if (ws_size >= off_q) {
    unsigned* bits = (unsigned*)((char*)d_ws + off_bits);
    build_bits_kernel<<<(unsigned)(mask_elems / 256), 256, 0, stream>>>(mask, bits);
    dim3 gfb(S_LEN / 64, B_SZ * NH);
    attn_fb<true><<<gfb, 512, 0, stream>>>(Q, K, V, mask, bits, out);
  } else {
    dim3 gfb(S_LEN / 64, B_SZ * NH);
    attn_fb<false><<<gfb, 512, 0, stream>>>(Q, K, V, mask, nullptr, out);
  }
}